// Round 4
// baseline (237.711 us; speedup 1.0000x reference)
//
#include <hip/hip_runtime.h>
#include <math.h>

// CapsuleLayer dynamic routing. B=256, IN=1152, K=8, J=10, D=16, 3 passes.
//
// Fast path (ws >= ~110MB): materialize u_hat bf16 once, stream it per pass.
//   K1  : u[i][b][160] bf16 = sum_k x[b,i,k] W[i,j,k,d]  (f32 compute)
//         + pass-0 partial s (c = 0.1 exactly) -> s_part.
//   SQ<0>: reduce 96 slabs + squash -> vdot = v0.
//   K2  : per (b,i): logit = vdot.u, softmax over j, s += c*u  (u read ONCE,
//         coalesced); block-reduce -> s_part.   SQ<1>: vdot += v1.
//   K2  ; SQ<2> -> out.
// Fallback: round-3 W-in-LDS fused path (passed at 101.7us).

typedef float f32x4 __attribute__((ext_vector_type(4)));

#define B_TOT 256
#define IN_CAPS 1152
#define OUT_CAPS 10
#define OUT_DIM 16
#define JD 160

static __device__ __forceinline__ unsigned short f2bf(float f) {
    unsigned int u = __float_as_uint(f);
    unsigned int r = (u + 0x7FFFu + ((u >> 16) & 1u)) >> 16;
    return (unsigned short)r;
}

// ====================== fast path =====================================
#define K1_IPB 12          // i per block/chunk
#define NCHUNK 96          // 1152/12
#define WPAD 1284          // 1280 + 4 pad
#define P_SLABS 96

#define U_BYTES   94371840ull                       // 1152*256*160*2
#define SP_BYTES  15728640ull                       // 96*256*160*4
#define VD_BYTES  163840ull                         // 256*160*4
#define WS_NEED   (U_BYTES + SP_BYTES + VD_BYTES)   // 110,264,320

__global__ __launch_bounds__(512, 4)
void k1_uhat(const float* __restrict__ x, const float* __restrict__ W,
             unsigned short* __restrict__ u, float* __restrict__ s_part) {
    __shared__ __align__(16) float wl[K1_IPB * WPAD];   // 61,632 B

    const int tid = threadIdx.x;
    const int bl  = tid & 63;          // lane = batch within tile
    const int g   = tid >> 6;          // wave = quad-group (W addr wave-uniform!)
    const int ch  = blockIdx.x;        // i-chunk 0..95
    const int bt  = blockIdx.y;        // b-tile 0..3
    const int b   = bt * 64 + bl;
    const int i0  = ch * K1_IPB;

    // stage W chunk [12][1280] -> [12][1284] (coalesced, conflict-free)
    for (int t = tid; t < K1_IPB * 320; t += 512) {
        const int il = t / 320, r4 = t % 320;
        f32x4 v = *(const f32x4*)(W + (size_t)(i0 + il) * 1280 + r4 * 4);
        *(f32x4*)(wl + il * WPAD + r4 * 4) = v;
    }
    __syncthreads();

    f32x4 sa[5];
    #pragma unroll
    for (int r = 0; r < 5; ++r) sa[r] = (f32x4){0.f, 0.f, 0.f, 0.f};

    #pragma unroll 1
    for (int il = 0; il < K1_IPB; ++il) {
        const float* xp = x + (size_t)b * (IN_CAPS * 8) + (size_t)(i0 + il) * 8;
        const f32x4 xa = *(const f32x4*)xp, xb = *(const f32x4*)(xp + 4);
        const float xk[8] = {xa.x, xa.y, xa.z, xa.w, xb.x, xb.y, xb.z, xb.w};

        #pragma unroll
        for (int r = 0; r < 5; ++r) {
            const int q = g * 5 + r, j = q >> 2, dq = q & 3;
            const f32x4* wp = (const f32x4*)(wl + il * WPAD + j * 128 + dq * 4);
            f32x4 acc = (f32x4){0.f, 0.f, 0.f, 0.f};
            #pragma unroll
            for (int k = 0; k < 8; ++k) acc += xk[k] * wp[k * 4];

            ushort4 h;
            h.x = f2bf(acc.x); h.y = f2bf(acc.y); h.z = f2bf(acc.z); h.w = f2bf(acc.w);
            *(ushort4*)(u + ((size_t)(i0 + il) * B_TOT + b) * JD + q * 4) = h;

            sa[r] += 0.1f * acc;
        }
    }

    // pass-0 partial: each (b, q) owned by exactly one thread -> direct store
    #pragma unroll
    for (int r = 0; r < 5; ++r)
        *(f32x4*)(s_part + ((size_t)ch * B_TOT + b) * JD + (g * 5 + r) * 4) = sa[r];
}

// routing pass: read u once, produce s_part.  grid (96 slices, 8 b-tiles), 256 thr.
__global__ __launch_bounds__(256, 3)
void k2_route(const unsigned short* __restrict__ u,
              const float* __restrict__ vdot,
              float* __restrict__ s_part) {
    __shared__ float smem[2 * 64 * 81];    // 41,472 B (vdot area, then reduce stage)

    const int tid  = threadIdx.x;
    const int lane = tid & 63;
    const int w    = tid >> 6;           // wave 0..3
    const int b_l  = lane >> 1;          // batch 0..31
    const int jq   = lane & 1;           // j half
    const int sl   = blockIdx.x;         // i-slice 0..95
    const int bt   = blockIdx.y;         // b-tile 0..7
    const int b    = bt * 32 + b_l;

    // stage vdot[b-tile] into LDS, stride 161 (odd -> bank-clean)
    for (int e = tid; e < 32 * JD; e += 256) {
        const int bb = e / JD, jd = e % JD;
        smem[bb * 161 + jd] = vdot[(size_t)(bt * 32 + bb) * JD + jd];
    }
    __syncthreads();

    float s[80];
    #pragma unroll
    for (int r = 0; r < 80; ++r) s[r] = 0.f;

    const int vbase = b_l * 161 + jq * 80;

    #pragma unroll 1
    for (int t = 0; t < 3; ++t) {
        const int i = sl * 12 + t * 4 + w;
        const uint4* up = (const uint4*)(u + ((size_t)i * B_TOT + b) * JD + jq * 80);
        uint4 uh[10];
        #pragma unroll
        for (int c = 0; c < 10; ++c) uh[c] = up[c];

        // logits for this lane's 5 j's (reduce over all 16 d, in-lane)
        float L[5];
        #pragma unroll
        for (int jj = 0; jj < 5; ++jj) {
            float acc = 0.f;
            #pragma unroll
            for (int c2 = 0; c2 < 2; ++c2) {
                const uint4 U = uh[jj * 2 + c2];
                const unsigned uu[4] = {U.x, U.y, U.z, U.w};
                #pragma unroll
                for (int wd = 0; wd < 4; ++wd) {
                    const unsigned v = uu[wd];
                    const float f0 = __uint_as_float(v << 16);
                    const float f1 = __uint_as_float(v & 0xFFFF0000u);
                    const int d = c2 * 8 + wd * 2;
                    acc = fmaf(smem[vbase + jj * 16 + d],     f0, acc);
                    acc = fmaf(smem[vbase + jj * 16 + d + 1], f1, acc);
                }
            }
            L[jj] = acc;
        }

        // softmax over 10 j (cross-half via lane^1)
        float m = fmaxf(fmaxf(fmaxf(L[0], L[1]), fmaxf(L[2], L[3])), L[4]);
        m = fmaxf(m, __shfl_xor(m, 1));
        float e5[5], Z = 0.f;
        #pragma unroll
        for (int jj = 0; jj < 5; ++jj) { e5[jj] = __expf(L[jj] - m); Z += e5[jj]; }
        Z += __shfl_xor(Z, 1);
        const float inv = 1.0f / Z;

        #pragma unroll
        for (int jj = 0; jj < 5; ++jj) {
            const float c = e5[jj] * inv;
            #pragma unroll
            for (int c2 = 0; c2 < 2; ++c2) {
                const uint4 U = uh[jj * 2 + c2];
                const unsigned uu[4] = {U.x, U.y, U.z, U.w};
                #pragma unroll
                for (int wd = 0; wd < 4; ++wd) {
                    const unsigned v = uu[wd];
                    const float f0 = __uint_as_float(v << 16);
                    const float f1 = __uint_as_float(v & 0xFFFF0000u);
                    const int d = c2 * 8 + wd * 2;
                    s[jj * 16 + d]     = fmaf(c, f0, s[jj * 16 + d]);
                    s[jj * 16 + d + 1] = fmaf(c, f1, s[jj * 16 + d + 1]);
                }
            }
        }
    }

    // block reduce over 4 waves (reuse smem; vdot no longer needed)
    __syncthreads();
    if (w >= 2) {
        float* st = smem + ((w - 2) * 64 + lane) * 81;
        #pragma unroll
        for (int r = 0; r < 80; ++r) st[r] = s[r];
    }
    __syncthreads();
    if (w < 2) {
        float* st = smem + (w * 64 + lane) * 81;
        #pragma unroll
        for (int r = 0; r < 80; ++r) s[r] += st[r];
        if (w == 1) {
            #pragma unroll
            for (int r = 0; r < 80; ++r) st[r] = s[r];   // own slot, no race
        }
    }
    __syncthreads();
    if (w == 0) {
        const float* st = smem + (64 + lane) * 81;
        #pragma unroll
        for (int r = 0; r < 80; ++r) s[r] += st[r];
        float* sp = s_part + ((size_t)sl * B_TOT + b) * JD + jq * 80;
        #pragma unroll
        for (int r4 = 0; r4 < 20; ++r4)
            *(f32x4*)(sp + r4 * 4) = (f32x4){s[r4*4], s[r4*4+1], s[r4*4+2], s[r4*4+3]};
    }
}

template<int PASS>
__global__ __launch_bounds__(256)
void k_squash(const float* __restrict__ s_part,
              float* __restrict__ vdot, float* __restrict__ out) {
    const int e = blockIdx.x * 256 + threadIdx.x;    // < 40960
    float s = 0.f;
    #pragma unroll 8
    for (int p = 0; p < P_SLABS; ++p)
        s += s_part[(size_t)p * (B_TOT * JD) + e];

    float t = s * s;
    t += __shfl_xor(t, 1);
    t += __shfl_xor(t, 2);
    t += __shfl_xor(t, 4);
    t += __shfl_xor(t, 8);
    const float scale = t / (1.0f + t) / sqrtf(t + 1e-7f);
    const float v = scale * s;

    if (PASS == 0)      vdot[e] = v;
    else if (PASS == 1) vdot[e] += v;
    else                out[e] = v;
}

// ====================== round-3 fallback path =========================
#define NSLICE 16
#define IPB 72
#define BPB 16
#define CHUNK 24
#define XROW 580
#define REDSTRIDE 2564
#define SPART3_ELEMS ((size_t)NSLICE * B_TOT * JD)
#define VDOT_ELEMS  ((size_t)B_TOT * JD)

template<int PASS>
__global__ __launch_bounds__(512, 1)
void caps_main(const float* __restrict__ x, const float* __restrict__ W,
               const float* __restrict__ vdot, float* __restrict__ s_part) {
    __shared__ __align__(16) float xs[BPB * XROW];
    __shared__ __align__(16) float wl[CHUNK * 1280];
    const int tid = threadIdx.x;
    const int dh = tid & 3, jq = (tid >> 2) & 1, bl = (tid >> 3) & 7, ig = tid >> 6;
    const int is = blockIdx.x, bg = blockIdx.y;
    const int b = bg * BPB + bl * 2, bL0 = bl * 2;
    for (int t = tid; t < BPB * 144; t += 512) {
        const int r = t / 144, c = t % 144;
        f32x4 v = *(const f32x4*)(x + (size_t)(bg * BPB + r) * (IN_CAPS * 8)
                                    + (size_t)is * (IPB * 8) + c * 4);
        *(f32x4*)(xs + r * XROW + c * 4) = v;
    }
    f32x4 vd[2][5];
    if (PASS > 0) {
        #pragma unroll
        for (int bt = 0; bt < 2; ++bt)
            #pragma unroll
            for (int jj = 0; jj < 5; ++jj)
                vd[bt][jj] = *(const f32x4*)(vdot + (size_t)(b + bt) * JD
                                                   + (jq * 5 + jj) * OUT_DIM + dh * 4);
    }
    __syncthreads();
    f32x4 sa[2][5];
    #pragma unroll
    for (int bt = 0; bt < 2; ++bt)
        #pragma unroll
        for (int jj = 0; jj < 5; ++jj) sa[bt][jj] = (f32x4){0.f, 0.f, 0.f, 0.f};
    for (int ch = 0; ch < 3; ++ch) {
        __syncthreads();
        {
            const f32x4* wg = (const f32x4*)(W + ((size_t)is * IPB + ch * CHUNK) * 1280);
            f32x4* wl4 = (f32x4*)wl;
            #pragma unroll
            for (int t = 0; t < 15; ++t) wl4[t * 512 + tid] = wg[t * 512 + tid];
        }
        __syncthreads();
        #pragma unroll
        for (int ip = 0; ip < 3; ++ip) {
            const int il = ig * 3 + ip;
            float xk[2][8];
            #pragma unroll
            for (int bt = 0; bt < 2; ++bt) {
                const f32x4* xr = (const f32x4*)(xs + (bL0 + bt) * XROW + (ch * CHUNK + il) * 8);
                const f32x4 a0 = xr[0], a1 = xr[1];
                xk[bt][0]=a0.x; xk[bt][1]=a0.y; xk[bt][2]=a0.z; xk[bt][3]=a0.w;
                xk[bt][4]=a1.x; xk[bt][5]=a1.y; xk[bt][6]=a1.z; xk[bt][7]=a1.w;
            }
            f32x4 uu[2][5];
            #pragma unroll
            for (int jj = 0; jj < 5; ++jj) {
                const f32x4* wp = (const f32x4*)(wl + il * 1280 + (jq * 5 + jj) * 128 + dh * 4);
                f32x4 a0 = (f32x4){0.f,0.f,0.f,0.f}, a1 = a0;
                #pragma unroll
                for (int k = 0; k < 8; ++k) {
                    const f32x4 wv = wp[k * 4];
                    a0 += xk[0][k] * wv; a1 += xk[1][k] * wv;
                }
                uu[0][jj] = a0; uu[1][jj] = a1;
            }
            if (PASS == 0) {
                #pragma unroll
                for (int bt = 0; bt < 2; ++bt)
                    #pragma unroll
                    for (int jj = 0; jj < 5; ++jj) sa[bt][jj] += 0.1f * uu[bt][jj];
            } else {
                #pragma unroll
                for (int bt = 0; bt < 2; ++bt) {
                    float L[5];
                    #pragma unroll
                    for (int jj = 0; jj < 5; ++jj) {
                        const f32x4 p = vd[bt][jj] * uu[bt][jj];
                        float tt = (p.x + p.y) + (p.z + p.w);
                        tt += __shfl_xor(tt, 1); tt += __shfl_xor(tt, 2);
                        L[jj] = tt;
                    }
                    float m = fmaxf(fmaxf(fmaxf(L[0], L[1]), fmaxf(L[2], L[3])), L[4]);
                    m = fmaxf(m, __shfl_xor(m, 4));
                    float e[5], Z = 0.f;
                    #pragma unroll
                    for (int jj = 0; jj < 5; ++jj) { e[jj] = __expf(L[jj] - m); Z += e[jj]; }
                    Z += __shfl_xor(Z, 4);
                    const float inv = 1.0f / Z;
                    #pragma unroll
                    for (int jj = 0; jj < 5; ++jj) sa[bt][jj] += (e[jj] * inv) * uu[bt][jj];
                }
            }
        }
    }
    __syncthreads();
    float* red = wl;
    #pragma unroll
    for (int bt = 0; bt < 2; ++bt)
        #pragma unroll
        for (int jj = 0; jj < 5; ++jj)
            *(f32x4*)(red + ig * REDSTRIDE
                          + ((bL0 + bt) * OUT_CAPS + (jq * 5 + jj)) * OUT_DIM + dh * 4)
                = sa[bt][jj];
    __syncthreads();
    {
        const size_t base = ((size_t)is * B_TOT + bg * BPB) * JD;
        #pragma unroll
        for (int r = 0; r < 5; ++r) {
            const int e = tid * 5 + r;
            float acc = 0.f;
            #pragma unroll
            for (int p = 0; p < 8; ++p) acc += red[p * REDSTRIDE + e];
            s_part[base + e] = acc;
        }
    }
}

template<int PASS>
__global__ __launch_bounds__(256)
void caps_squash(const float* __restrict__ s_part,
                 float* __restrict__ vdot, float* __restrict__ out) {
    const int e = blockIdx.x * 256 + threadIdx.x;
    float s = 0.f;
    #pragma unroll
    for (int p = 0; p < NSLICE; ++p) s += s_part[(size_t)p * (B_TOT * JD) + e];
    float t = s * s;
    t += __shfl_xor(t, 1); t += __shfl_xor(t, 2);
    t += __shfl_xor(t, 4); t += __shfl_xor(t, 8);
    const float scale = t / (1.0f + t) / sqrtf(t + 1e-7f);
    const float v = scale * s;
    if (PASS == 0)      vdot[e] = v;
    else if (PASS == 1) vdot[e] += v;
    else                out[e] = v;
}

// ultra-fallback: round-1 fused (ws ~ 0)
#define FB_NGROUPS 32
#define FB_THREADS (FB_NGROUPS * OUT_DIM)
#define FB_ITERS (IN_CAPS / FB_NGROUPS)
__global__ __launch_bounds__(FB_THREADS)
void caps_routing_kernel(const float* __restrict__ x, const float* __restrict__ W,
                         float* __restrict__ out) {
    __shared__ __align__(16) float xsf[IN_CAPS * 8];
    __shared__ float sredf[FB_NGROUPS * JD];
    __shared__ float vdot_lds[JD];
    const int b = blockIdx.x, tid = threadIdx.x;
    const int g = tid >> 4, d = tid & 15;
    {
        const float4* xg = reinterpret_cast<const float4*>(x + (size_t)b * IN_CAPS * 8);
        float4* xl = reinterpret_cast<float4*>(xsf);
        for (int t = tid; t < IN_CAPS * 2; t += FB_THREADS) xl[t] = xg[t];
    }
    __syncthreads();
    for (int pass = 0; pass < 3; ++pass) {
        float vdot_reg[OUT_CAPS];
        if (pass > 0) {
            #pragma unroll
            for (int j = 0; j < OUT_CAPS; ++j) vdot_reg[j] = vdot_lds[j * OUT_DIM + d];
        }
        float s_loc[OUT_CAPS];
        #pragma unroll
        for (int j = 0; j < OUT_CAPS; ++j) s_loc[j] = 0.f;
        for (int it = 0; it < FB_ITERS; ++it) {
            const int i = it * FB_NGROUPS + g;
            float xk[8];
            {
                const float4* xr = reinterpret_cast<const float4*>(xsf + i * 8);
                float4 a0 = xr[0], a1 = xr[1];
                xk[0]=a0.x; xk[1]=a0.y; xk[2]=a0.z; xk[3]=a0.w;
                xk[4]=a1.x; xk[5]=a1.y; xk[6]=a1.z; xk[7]=a1.w;
            }
            const float* wpf = W + (size_t)i * 1280 + d;
            float u[OUT_CAPS];
            #pragma unroll
            for (int j = 0; j < OUT_CAPS; ++j) {
                float acc = 0.f;
                #pragma unroll
                for (int k = 0; k < 8; ++k) acc = fmaf(xk[k], wpf[j * 128 + k * OUT_DIM], acc);
                u[j] = acc;
            }
            if (pass == 0) {
                #pragma unroll
                for (int j = 0; j < OUT_CAPS; ++j) s_loc[j] = fmaf(0.1f, u[j], s_loc[j]);
            } else {
                float logit[OUT_CAPS];
                #pragma unroll
                for (int j = 0; j < OUT_CAPS; ++j) {
                    float t2 = vdot_reg[j] * u[j];
                    t2 += __shfl_xor(t2, 1); t2 += __shfl_xor(t2, 2);
                    t2 += __shfl_xor(t2, 4); t2 += __shfl_xor(t2, 8);
                    logit[j] = t2;
                }
                float m = logit[0];
                #pragma unroll
                for (int j = 1; j < OUT_CAPS; ++j) m = fmaxf(m, logit[j]);
                float Z = 0.f, e[OUT_CAPS];
                #pragma unroll
                for (int j = 0; j < OUT_CAPS; ++j) { e[j] = expf(logit[j] - m); Z += e[j]; }
                const float invZ = 1.0f / Z;
                #pragma unroll
                for (int j = 0; j < OUT_CAPS; ++j) s_loc[j] = fmaf(e[j] * invZ, u[j], s_loc[j]);
            }
        }
        #pragma unroll
        for (int j = 0; j < OUT_CAPS; ++j) sredf[g * JD + j * OUT_DIM + d] = s_loc[j];
        __syncthreads();
        if (tid < JD) {
            float sv = 0.f;
            #pragma unroll 8
            for (int gg = 0; gg < FB_NGROUPS; ++gg) sv += sredf[gg * JD + tid];
            float t2 = sv * sv;
            t2 += __shfl_xor(t2, 1); t2 += __shfl_xor(t2, 2);
            t2 += __shfl_xor(t2, 4); t2 += __shfl_xor(t2, 8);
            const float scale = t2 / (1.0f + t2) / sqrtf(t2 + 1e-7f);
            const float v = scale * sv;
            if (pass == 2) out[(size_t)b * JD + tid] = v;
            else vdot_lds[tid] = (pass == 0) ? v : (vdot_lds[tid] + v);
        }
        __syncthreads();
    }
}

extern "C" void kernel_launch(void* const* d_in, const int* in_sizes, int n_in,
                              void* d_out, int out_size, void* d_ws, size_t ws_size,
                              hipStream_t stream) {
    const float* x = (const float*)d_in[0];
    const float* W = (const float*)d_in[1];
    float* out = (float*)d_out;

    if (ws_size >= WS_NEED) {
        unsigned short* u = (unsigned short*)d_ws;
        float* s_part = (float*)((char*)d_ws + U_BYTES);
        float* vdot   = (float*)((char*)d_ws + U_BYTES + SP_BYTES);
        const int gSQ = (B_TOT * JD) / 256;   // 160

        k1_uhat<<<dim3(NCHUNK, 4), 512, 0, stream>>>(x, W, u, s_part);
        k_squash<0><<<gSQ, 256, 0, stream>>>(s_part, vdot, out);
        k2_route<<<dim3(P_SLABS, 8), 256, 0, stream>>>(u, vdot, s_part);
        k_squash<1><<<gSQ, 256, 0, stream>>>(s_part, vdot, out);
        k2_route<<<dim3(P_SLABS, 8), 256, 0, stream>>>(u, vdot, s_part);
        k_squash<2><<<gSQ, 256, 0, stream>>>(s_part, vdot, out);
    } else if (ws_size >= (SPART3_ELEMS + VDOT_ELEMS) * sizeof(float)) {
        float* s_part = (float*)d_ws;
        float* vdot   = (float*)d_ws + SPART3_ELEMS;
        const dim3 gA(NSLICE, B_TOT / BPB);
        const int  gB = (B_TOT * JD) / 256;
        caps_main<0><<<gA, 512, 0, stream>>>(x, W, vdot, s_part);
        caps_squash<0><<<gB, 256, 0, stream>>>(s_part, vdot, out);
        caps_main<1><<<gA, 512, 0, stream>>>(x, W, vdot, s_part);
        caps_squash<1><<<gB, 256, 0, stream>>>(s_part, vdot, out);
        caps_main<2><<<gA, 512, 0, stream>>>(x, W, vdot, s_part);
        caps_squash<2><<<gB, 256, 0, stream>>>(s_part, vdot, out);
    } else {
        caps_routing_kernel<<<B_TOT, FB_THREADS, 0, stream>>>(x, W, out);
    }
}

// Round 5
// 91.966 us; speedup vs baseline: 2.5848x; 2.5848x over previous
//
#include <hip/hip_runtime.h>
#include <math.h>

// CapsuleLayer dynamic routing. B=256, IN=1152, K=8, J=10, D=16, 3 passes.
//
// Strategy: recompute u_hat every pass, but on the MFMA pipe.
//  prep : W -> wht bf16 [i][jd][k] (k,d transposed), x -> xht bf16 [i][b][k].
//  caps_pass<P>: grid (48 i-slices x 16 b-tiles), 256 thr = 4 waves.
//    Wave handles 6 i's for one 16-b tile. Per i: 10x mfma_f32_16x16x32_bf16
//    (A = W-tile [16jd x 8k pad32], B = x [8k pad32 x 16b]) -> u fragments
//    (lane: b=l&15, d=(l>>4)*4+r, j=tile). Logit = 4 in-lane FMA + 2 shfl;
//    softmax in-lane over 10 j; s-frags accumulate in regs. 4-wave LDS
//    reduce -> s_part slab. Deterministic, no atomics.
//  k_squash<P>: reduce 48 slabs + squash -> vdot / out.
// Algebra: logits at pass t = (sum of previous v)·u_hat; pass 0 c = 0.1.

typedef float f32x4 __attribute__((ext_vector_type(4)));
typedef short bf16x8 __attribute__((ext_vector_type(8)));

#define B_TOT 256
#define IN_CAPS 1152
#define OUT_CAPS 10
#define OUT_DIM 16
#define JD 160

#define NSLICE 48
#define IPB 24            // i per block (6 per wave)
#define NBT 16            // b-tiles of 16

#define WHT_BYTES (1152ull * 160 * 8 * 2)       // 2,949,120
#define XHT_BYTES (1152ull * 256 * 8 * 2)       // 4,718,592
#define SP_BYTES  ((size_t)NSLICE * B_TOT * JD * 4)  // 7,864,320
#define VD_BYTES  ((size_t)B_TOT * JD * 4)      // 163,840
#define WS_NEED   (WHT_BYTES + XHT_BYTES + SP_BYTES + VD_BYTES)

static __device__ __forceinline__ unsigned f2bf(float f) {
    unsigned u = __float_as_uint(f);
    return (u + 0x7FFFu + ((u >> 16) & 1u)) >> 16;
}

// wht[i][jd][k] <- W[i][j][k][d], packed pairs (k, k+1)
__global__ __launch_bounds__(256)
void prep_w(const float* __restrict__ W, unsigned* __restrict__ whu) {
    const int g = blockIdx.x * 256 + threadIdx.x;   // < 737280
    const int i = g / 640, p = g % 640;
    const int jd = p >> 2, kk = (p & 3) * 2;
    const int j = jd >> 4, d = jd & 15;
    const int base = i * 1280 + j * 128 + d;
    const unsigned lo = f2bf(W[base + kk * 16]);
    const unsigned hi = f2bf(W[base + (kk + 1) * 16]);
    whu[g] = lo | (hi << 16);
}

// xht[i][b][k] <- x[b][i][k], packed pairs
__global__ __launch_bounds__(256)
void prep_x(const float* __restrict__ x, unsigned* __restrict__ xhu) {
    const int g = blockIdx.x * 256 + threadIdx.x;   // < 1179648
    const int i = g / 1024, r = g % 1024;
    const int b = r >> 2, kk = (r & 3) * 2;
    const int in = b * 9216 + i * 8 + kk;
    const unsigned lo = f2bf(x[in]);
    const unsigned hi = f2bf(x[in + 1]);
    xhu[g] = lo | (hi << 16);
}

template<int PASS>
__global__ __launch_bounds__(256, 2)
void caps_pass(const unsigned short* __restrict__ wht,
               const unsigned short* __restrict__ xht,
               const float* __restrict__ vdot,
               float* __restrict__ s_part) {
    __shared__ float red[64 * 164];   // 41,984 B (4 wave-slabs of 16b x 160jd)

    const int t  = threadIdx.x;
    const int l  = t & 63;
    const int w  = t >> 6;            // wave 0..3
    const int is = blockIdx.x;        // i-slice 0..47
    const int b0 = blockIdx.y * 16;   // b-tile base
    const int m  = l & 15;            // A-row / B-col / C-col index
    const int q  = l >> 4;            // k-quad (input) / d-subrow group (output)

    // vdot fragments, i-invariant: vd[j][r] = vdot[b0+m][j][q*4+r]
    f32x4 vd[10];
    if (PASS > 0) {
        #pragma unroll
        for (int jt = 0; jt < 10; ++jt)
            vd[jt] = *(const f32x4*)(vdot + (b0 + m) * JD + jt * 16 + q * 4);
    }

    f32x4 s[10];
    #pragma unroll
    for (int jt = 0; jt < 10; ++jt) s[jt] = (f32x4){0.f, 0.f, 0.f, 0.f};

    const bf16x8 zfrag = {0, 0, 0, 0, 0, 0, 0, 0};

    #pragma unroll 1
    for (int ii = 0; ii < 6; ++ii) {
        const int i = is * IPB + w * 6 + ii;

        // B-frag: lanes with q==0 hold x[b0+m][i][k=0..7]; k>=8 zero-padded
        bf16x8 xb = zfrag;
        if (q == 0)
            xb = *(const bf16x8*)(xht + ((size_t)i * B_TOT + b0 + m) * 8);

        f32x4 u[10];
        #pragma unroll
        for (int jt = 0; jt < 10; ++jt) {
            bf16x8 af = zfrag;   // A-frag: W[i][jt*16+m][k=0..7]
            if (q == 0)
                af = *(const bf16x8*)(wht + ((size_t)i * JD + jt * 16 + m) * 8);
            u[jt] = __builtin_amdgcn_mfma_f32_16x16x32_bf16(
                        af, xb, (f32x4){0.f, 0.f, 0.f, 0.f}, 0, 0, 0);
        }

        if (PASS == 0) {
            #pragma unroll
            for (int jt = 0; jt < 10; ++jt) s[jt] += 0.1f * u[jt];
        } else {
            // logit[j] = sum_d vdot.u : 4 in-lane FMA + reduce lanes {l,l^16,l^32}
            float L[10];
            #pragma unroll
            for (int jt = 0; jt < 10; ++jt) {
                const f32x4 p = vd[jt] * u[jt];
                float e = (p.x + p.y) + (p.z + p.w);
                e += __shfl_xor(e, 16);
                e += __shfl_xor(e, 32);
                L[jt] = e;
            }
            float mx = L[0];
            #pragma unroll
            for (int jt = 1; jt < 10; ++jt) mx = fmaxf(mx, L[jt]);
            float Z = 0.f;
            #pragma unroll
            for (int jt = 0; jt < 10; ++jt) { L[jt] = __expf(L[jt] - mx); Z += L[jt]; }
            const float inv = 1.0f / Z;
            #pragma unroll
            for (int jt = 0; jt < 10; ++jt) s[jt] += (L[jt] * inv) * u[jt];
        }
    }

    // 4-wave reduce through LDS, then coalesced slab store
    {
        float* rp = red + (w * 16 + m) * 164 + q * 4;
        #pragma unroll
        for (int jt = 0; jt < 10; ++jt)
            *(f32x4*)(rp + jt * 16) = s[jt];
    }
    __syncthreads();
    {
        const size_t base = ((size_t)is * B_TOT + b0) * JD;
        #pragma unroll
        for (int n = 0; n < 10; ++n) {
            const int e  = t + n * 256;      // 0..2559
            const int bl = e / JD, jd = e % JD;
            const float acc = red[bl * 164 + jd] + red[(16 + bl) * 164 + jd]
                            + red[(32 + bl) * 164 + jd] + red[(48 + bl) * 164 + jd];
            s_part[base + (size_t)bl * JD + jd] = acc;
        }
    }
}

template<int PASS>
__global__ __launch_bounds__(256)
void k_squash(const float* __restrict__ s_part,
              float* __restrict__ vdot, float* __restrict__ out) {
    const int e = blockIdx.x * 256 + threadIdx.x;    // < 40960
    float s = 0.f;
    #pragma unroll 8
    for (int p = 0; p < NSLICE; ++p)
        s += s_part[(size_t)p * (B_TOT * JD) + e];

    float t = s * s;
    t += __shfl_xor(t, 1);
    t += __shfl_xor(t, 2);
    t += __shfl_xor(t, 4);
    t += __shfl_xor(t, 8);
    const float scale = t / (1.0f + t) / sqrtf(t + 1e-7f);
    const float v = scale * s;

    if (PASS == 0)      vdot[e] = v;
    else if (PASS == 1) vdot[e] += v;
    else                out[e] = v;
}

// ---------- fallback: round-1 fused kernel (ws too small; shouldn't happen) ----------
#define FB_NGROUPS 32
#define FB_THREADS (FB_NGROUPS * OUT_DIM)
#define FB_ITERS (IN_CAPS / FB_NGROUPS)
__global__ __launch_bounds__(FB_THREADS)
void caps_routing_kernel(const float* __restrict__ x, const float* __restrict__ W,
                         float* __restrict__ out) {
    __shared__ __align__(16) float xsf[IN_CAPS * 8];
    __shared__ float sredf[FB_NGROUPS * JD];
    __shared__ float vdot_lds[JD];
    const int b = blockIdx.x, tid = threadIdx.x;
    const int g = tid >> 4, d = tid & 15;
    {
        const float4* xg = reinterpret_cast<const float4*>(x + (size_t)b * IN_CAPS * 8);
        float4* xl = reinterpret_cast<float4*>(xsf);
        for (int t = tid; t < IN_CAPS * 2; t += FB_THREADS) xl[t] = xg[t];
    }
    __syncthreads();
    for (int pass = 0; pass < 3; ++pass) {
        float vdot_reg[OUT_CAPS];
        if (pass > 0) {
            #pragma unroll
            for (int j = 0; j < OUT_CAPS; ++j) vdot_reg[j] = vdot_lds[j * OUT_DIM + d];
        }
        float s_loc[OUT_CAPS];
        #pragma unroll
        for (int j = 0; j < OUT_CAPS; ++j) s_loc[j] = 0.f;
        for (int it = 0; it < FB_ITERS; ++it) {
            const int i = it * FB_NGROUPS + g;
            float xk[8];
            {
                const float4* xr = reinterpret_cast<const float4*>(xsf + i * 8);
                float4 a0 = xr[0], a1 = xr[1];
                xk[0]=a0.x; xk[1]=a0.y; xk[2]=a0.z; xk[3]=a0.w;
                xk[4]=a1.x; xk[5]=a1.y; xk[6]=a1.z; xk[7]=a1.w;
            }
            const float* wpf = W + (size_t)i * 1280 + d;
            float u[OUT_CAPS];
            #pragma unroll
            for (int j = 0; j < OUT_CAPS; ++j) {
                float acc = 0.f;
                #pragma unroll
                for (int k = 0; k < 8; ++k) acc = fmaf(xk[k], wpf[j * 128 + k * OUT_DIM], acc);
                u[j] = acc;
            }
            if (pass == 0) {
                #pragma unroll
                for (int j = 0; j < OUT_CAPS; ++j) s_loc[j] = fmaf(0.1f, u[j], s_loc[j]);
            } else {
                float logit[OUT_CAPS];
                #pragma unroll
                for (int j = 0; j < OUT_CAPS; ++j) {
                    float t2 = vdot_reg[j] * u[j];
                    t2 += __shfl_xor(t2, 1); t2 += __shfl_xor(t2, 2);
                    t2 += __shfl_xor(t2, 4); t2 += __shfl_xor(t2, 8);
                    logit[j] = t2;
                }
                float m = logit[0];
                #pragma unroll
                for (int j = 1; j < OUT_CAPS; ++j) m = fmaxf(m, logit[j]);
                float Z = 0.f, e[OUT_CAPS];
                #pragma unroll
                for (int j = 0; j < OUT_CAPS; ++j) { e[j] = expf(logit[j] - m); Z += e[j]; }
                const float invZ = 1.0f / Z;
                #pragma unroll
                for (int j = 0; j < OUT_CAPS; ++j) s_loc[j] = fmaf(e[j] * invZ, u[j], s_loc[j]);
            }
        }
        #pragma unroll
        for (int j = 0; j < OUT_CAPS; ++j) sredf[g * JD + j * OUT_DIM + d] = s_loc[j];
        __syncthreads();
        if (tid < JD) {
            float sv = 0.f;
            #pragma unroll 8
            for (int gg = 0; gg < FB_NGROUPS; ++gg) sv += sredf[gg * JD + tid];
            float t2 = sv * sv;
            t2 += __shfl_xor(t2, 1); t2 += __shfl_xor(t2, 2);
            t2 += __shfl_xor(t2, 4); t2 += __shfl_xor(t2, 8);
            const float scale = t2 / (1.0f + t2) / sqrtf(t2 + 1e-7f);
            const float v = scale * sv;
            if (pass == 2) out[(size_t)b * JD + tid] = v;
            else vdot_lds[tid] = (pass == 0) ? v : (vdot_lds[tid] + v);
        }
        __syncthreads();
    }
}

extern "C" void kernel_launch(void* const* d_in, const int* in_sizes, int n_in,
                              void* d_out, int out_size, void* d_ws, size_t ws_size,
                              hipStream_t stream) {
    const float* x = (const float*)d_in[0];
    const float* W = (const float*)d_in[1];
    float* out = (float*)d_out;

    if (ws_size >= WS_NEED) {
        unsigned short* wht = (unsigned short*)d_ws;
        unsigned short* xht = (unsigned short*)((char*)d_ws + WHT_BYTES);
        float* s_part = (float*)((char*)d_ws + WHT_BYTES + XHT_BYTES);
        float* vdot   = (float*)((char*)d_ws + WHT_BYTES + XHT_BYTES + SP_BYTES);

        prep_w<<<2880, 256, 0, stream>>>(W, (unsigned*)wht);
        prep_x<<<4608, 256, 0, stream>>>(x, (unsigned*)xht);

        const dim3 gR(NSLICE, NBT);
        const int gSQ = (B_TOT * JD) / 256;   // 160

        caps_pass<0><<<gR, 256, 0, stream>>>(wht, xht, vdot, s_part);
        k_squash<0><<<gSQ, 256, 0, stream>>>(s_part, vdot, out);
        caps_pass<1><<<gR, 256, 0, stream>>>(wht, xht, vdot, s_part);
        k_squash<1><<<gSQ, 256, 0, stream>>>(s_part, vdot, out);
        caps_pass<2><<<gR, 256, 0, stream>>>(wht, xht, vdot, s_part);
        k_squash<2><<<gSQ, 256, 0, stream>>>(s_part, vdot, out);
    } else {
        caps_routing_kernel<<<B_TOT, FB_THREADS, 0, stream>>>(x, W, out);
    }
}